// Round 15
// baseline (149.996 us; speedup 1.0000x reference)
//
#include <hip/hip_runtime.h>
#include <hip/hip_bf16.h>
#include <cstdint>

// CIN chain: B=1024, F0=32, EMB=64, layers 128/128/128.
// cur[b,k,e] = sum_{i,j} x[b,i,e]*h[b,j,e]*W[i*fi+j,k]
//
// R15: fold the direct GEMM into cin_fused. R14's split (fused -> S ->
// cin_direct) pays a launch gap + 10 MB S round-trip for work whose
// inputs (S[b,:]) are block-local. Now: S tiles go to 8 KB LDS (sS);
// the direct GEMM out[b,k] = <S[b,:], Wd[:,k]> + 64*bias runs in-kernel
// (B-fragment n=lr -> batch, lanes>=2 discarded; A = packed-Wt rows).
// The 16 KB xchg buffer is gone: split-K hidden partials exchange
// through the dead hT slot itself (hT layout, barrier-separated).
// LDS 52 KB. Two launches total (pack, fused).

typedef _Float16 half8  __attribute__((ext_vector_type(8)));
typedef _Float16 half4_ __attribute__((ext_vector_type(4)));
typedef _Float16 half2_ __attribute__((ext_vector_type(2)));
typedef float    f32x4  __attribute__((ext_vector_type(4)));

// Pack W (fan_in,128) f32 -> chunked f16 Wt[c][m][kk] = W[c*32+kk][m].
__global__ void pack_w_all(const float* __restrict__ W0, _Float16* __restrict__ Wt0,
                           const float* __restrict__ W1, _Float16* __restrict__ Wt1,
                           const float* __restrict__ W2, _Float16* __restrict__ Wt2)
{
    __shared__ _Float16 ldsT[128 * 33];
    const int blk = blockIdx.x, t = threadIdx.x;
    const float* W;
    _Float16* Wt;
    int c;
    if (blk < 32)       { W = W0; Wt = Wt0; c = blk; }
    else if (blk < 96)  { W = W1; Wt = Wt1; c = blk - 32; }
    else                { W = W2; Wt = Wt2; c = blk - 96; }

    for (int p = t; p < 32 * 128; p += 256) {
        int kk = p >> 7, m = p & 127;
        ldsT[m * 33 + kk] = (_Float16)W[(size_t)(c * 32 + kk) * 128 + m];
    }
    __syncthreads();
    int m = t >> 1, kk0 = (t & 1) * 16;
    half8 v0, v1;
#pragma unroll
    for (int i = 0; i < 8; ++i) {
        v0[i] = ldsT[m * 33 + kk0 + i];
        v1[i] = ldsT[m * 33 + kk0 + 8 + i];
    }
    *(half8*)(Wt + (size_t)c * 4096 + t * 16)     = v0;
    *(half8*)(Wt + (size_t)c * 4096 + t * 16 + 8) = v1;
}

// Fused hidden + S + direct kernel. Block = 2 batches, 4 waves (bb x ks).
__global__ __launch_bounds__(256, 2)
void cin_fused(const float* __restrict__ x,          // (1024,32,64) f32
               const _Float16* __restrict__ Wt0,
               const _Float16* __restrict__ Wt1,
               const _Float16* __restrict__ Wt2,
               const float* __restrict__ bs0,
               const float* __restrict__ bs1,
               const float* __restrict__ bs2,
               float* __restrict__ out)               // (1024,256) f32
{
    __shared__ alignas(16) char smem[53248];
    _Float16* slotA = (_Float16*)smem;                 // 18 KB: hT0 / hJ images
    _Float16* slotB = (_Float16*)(smem + 18432);       // 18 KB: hT1 / partials
    _Float16* sX    = (_Float16*)(smem + 36864);       // 8 KB: x [bb][i*64+e]
    _Float16* sS    = (_Float16*)(smem + 45056);       // 8 KB: S [b_local][fan]

    const int t = threadIdx.x, lane = t & 63, w = t >> 6;
    const int ks = w & 1, bb = w >> 1;
    const int lr = lane & 15, q = lane >> 4;
    const int b0 = blockIdx.x * 2;

    // prologue: x -> sX [i][e]; hT0 [e][i] pitch 40 -> slotA
    {
        const float4* xv = (const float4*)(x + (size_t)b0 * 2048);
#pragma unroll
        for (int s = 0; s < 4; ++s) {
            int p4 = t + s * 256;
            float4 v = xv[p4];
            int bb2 = p4 >> 9, idx = (p4 & 511) * 4;
            int i = idx >> 6, e0 = idx & 63;
            _Float16 h0 = (_Float16)v.x, h1 = (_Float16)v.y;
            _Float16 h2 = (_Float16)v.z, h3 = (_Float16)v.w;
            half4_ pk = {h0, h1, h2, h3};
            *(half4_*)(sX + bb2 * 2048 + i * 64 + e0) = pk;
            _Float16* hb = slotA + bb2 * 2560;
            hb[(e0 + 0) * 40 + i] = h0;
            hb[(e0 + 1) * 40 + i] = h1;
            hb[(e0 + 2) * 40 + i] = h2;
            hb[(e0 + 3) * 40 + i] = h3;
        }
    }
    __syncthreads();

    f32x4 acc[4][4];

    // barrier-free 2-deep pipelined hidden K-loop (M=64 rows, split-K by ks)
    auto kloop = [&](const _Float16* WtL, int cBeg, int cEnd, int ish,
                     const _Float16* hbase, int ph) {
#pragma unroll
        for (int mt = 0; mt < 4; ++mt)
#pragma unroll
            for (int nt = 0; nt < 4; ++nt)
                acc[mt][nt] = f32x4{0.0f, 0.0f, 0.0f, 0.0f};
        const _Float16* aG = WtL + lr * 32 + q * 8;
        const _Float16* hP = hbase + bb * (ph << 6) + lr * ph + q * 8;
        const _Float16* xP = sX + bb * 2048 + lr;
        half8 afA[4], afB[4], hvA[4], hvB[4];
        _Float16 xsA[4], xsB[4];
        auto pf = [&](half8* af, half8* hv, _Float16* xs, int c) {
            const int i  = c >> ish;
            const int j0 = (c - (i << ish)) << 5;
            const _Float16* ag = aG + (size_t)c * 4096;
#pragma unroll
            for (int mt = 0; mt < 4; ++mt) af[mt] = *(const half8*)(ag + mt * 512);
#pragma unroll
            for (int nt = 0; nt < 4; ++nt) {
                hv[nt] = *(const half8*)(hP + nt * (ph << 4) + j0);
                xs[nt] = xP[(i << 6) + (nt << 4)];
            }
        };
        auto cp = [&](half8* af, half8* hv, _Float16* xs) {
#pragma unroll
            for (int nt = 0; nt < 4; ++nt) {
                half2_ xv2 = {xs[nt], xs[nt]};
                half8 xv8 = __builtin_shufflevector(xv2, xv2, 0, 1, 0, 1, 0, 1, 0, 1);
                half8 bf = hv[nt] * xv8;
#pragma unroll
                for (int mt = 0; mt < 4; ++mt)
                    acc[mt][nt] = __builtin_amdgcn_mfma_f32_16x16x32_f16(
                        af[mt], bf, acc[mt][nt], 0, 0, 0);
            }
        };
        pf(afA, hvA, xsA, cBeg);
        for (int c = cBeg; c < cEnd; c += 2) {
            pf(afB, hvB, xsB, c + 1);
            cp(afA, hvA, xsA);
            if (c + 2 < cEnd) pf(afA, hvA, xsA, c + 2);
            cp(afB, hvB, xsB);
        }
    };

    // S_l[b][i*fi+j] = sum_e x[i,e]*h[j,e]  -> sS (LDS). Wave does i-tile=ks.
    auto sgemm = [&](const _Float16* hJ, int jp, int fi, int fan) {
        const _Float16* axp = sX + bb * 2048 + (ks * 16 + lr) * 64 + q * 8;
        const int njt = fi >> 4;
        for (int jt = 0; jt < njt; ++jt) {
            f32x4 sa = {0.0f, 0.0f, 0.0f, 0.0f};
#pragma unroll
            for (int c2 = 0; c2 < 2; ++c2) {
                half8 a = *(const half8*)(axp + c2 * 32);
                half8 b = *(const half8*)(hJ + (jt * 16 + lr) * jp + q * 8 + c2 * 32);
                sa = __builtin_amdgcn_mfma_f32_16x16x32_f16(a, b, sa, 0, 0, 0);
            }
#pragma unroll
            for (int r = 0; r < 4; ++r)
                sS[bb * fan + (ks * 16 + q * 4 + r) * fi + jt * 16 + lr]
                    = (_Float16)sa[r];
        }
    };

    // direct GEMM: out[b, ob+kl] = <sS[b,:], Wd[:,kl]> + 64*bias[dm0+kl]
    auto direct = [&](const _Float16* WtL, int fan, int nch, int dm0, int ob,
                      const float* biasL, int ntile) {
        for (int tt = w; tt < ntile; tt += 4) {
            const _Float16* aG2 = WtL + (dm0 + tt * 16 + lr) * 32 + q * 8;
            const _Float16* bP  = sS + (lr & 1) * fan + q * 8;
            f32x4 da = {0.0f, 0.0f, 0.0f, 0.0f};
            half8 aA = *(const half8*)(aG2);
            half8 bA = *(const half8*)(bP);
            for (int c = 0; c < nch; c += 2) {
                half8 aB = *(const half8*)(aG2 + (size_t)(c + 1) * 4096);
                half8 bB = *(const half8*)(bP + (c + 1) * 32);
                da = __builtin_amdgcn_mfma_f32_16x16x32_f16(aA, bA, da, 0, 0, 0);
                if (c + 2 < nch) {
                    aA = *(const half8*)(aG2 + (size_t)(c + 2) * 4096);
                    bA = *(const half8*)(bP + (c + 2) * 32);
                }
                da = __builtin_amdgcn_mfma_f32_16x16x32_f16(aB, bB, da, 0, 0, 0);
            }
            if (lr < 2) {
                int b = b0 + lr;
#pragma unroll
                for (int r = 0; r < 4; ++r) {
                    int kl = tt * 16 + q * 4 + r;
                    out[(size_t)b * 256 + ob + kl] = da[r] + 64.0f * biasL[dm0 + kl];
                }
            }
        }
    };

    // ks=1 hidden partial -> target slot, hT layout [e*72 + j] (vector half4)
    auto partial_out = [&](_Float16* slot) {
#pragma unroll
        for (int mt = 0; mt < 4; ++mt)
#pragma unroll
            for (int nt = 0; nt < 4; ++nt) {
                int e = nt * 16 + lr;
                int j = mt * 16 + q * 4;
                half4_ pv;
#pragma unroll
                for (int r = 0; r < 4; ++r) pv[r] = (_Float16)acc[mt][nt][r];
                *(half4_*)(slot + bb * 4608 + e * 72 + j) = pv;
            }
    };

    // ---- phase 0 ----
    sgemm(sX + bb * 2048, 64, 32, 1024);               // S0 = x @ x^T -> sS
    __syncthreads();                                   // sS ready
    direct(Wt0, 1024, 32, 64, 0, bs0, 4);              // out cols 0..63
    kloop(Wt0, ks * 16, ks * 16 + 16, 0, slotA, 40);   // hidden rows 0..63
    if (ks == 1) partial_out(slotB);                   // slotB virgin
    __syncthreads();
    if (ks == 0) {
        // combine + bias -> hT1 (slotB, same addresses) + hJ1 (slotA scatter)
#pragma unroll
        for (int mt = 0; mt < 4; ++mt)
#pragma unroll
            for (int nt = 0; nt < 4; ++nt) {
                int e = nt * 16 + lr;
                int j = mt * 16 + q * 4;
                half4_ pv = *(const half4_*)(slotB + bb * 4608 + e * 72 + j);
                half4_ vh;
#pragma unroll
                for (int r = 0; r < 4; ++r) {
                    float v = acc[mt][nt][r] + (float)pv[r] + bs0[j + r];
                    vh[r] = (_Float16)v;
                    slotA[bb * 4608 + (j + r) * 72 + e] = (_Float16)v;
                }
                *(half4_*)(slotB + bb * 4608 + e * 72 + j) = vh;
            }
    }
    __syncthreads();

    // ---- phase 1 ----
    sgemm(slotA + bb * 4608, 72, 64, 2048);            // S1 = x @ h1^T
    __syncthreads();
    direct(Wt1, 2048, 64, 64, 64, bs1, 4);             // out cols 64..127
    kloop(Wt1, ks * 32, ks * 32 + 32, 1, slotB, 72);   // hidden rows 0..63
    __syncthreads();                                   // slotB (hT1) reads done
    if (ks == 1) partial_out(slotB);                   // reuse dead hT1 region
    __syncthreads();
    if (ks == 0) {
        // combine + bias -> hJ2 only (slotA scatter)
#pragma unroll
        for (int mt = 0; mt < 4; ++mt)
#pragma unroll
            for (int nt = 0; nt < 4; ++nt) {
                int e = nt * 16 + lr;
                int j = mt * 16 + q * 4;
                half4_ pv = *(const half4_*)(slotB + bb * 4608 + e * 72 + j);
#pragma unroll
                for (int r = 0; r < 4; ++r)
                    slotA[bb * 4608 + (j + r) * 72 + e]
                        = (_Float16)(acc[mt][nt][r] + (float)pv[r] + bs1[j + r]);
            }
    }
    __syncthreads();

    // ---- phase 2 (no hidden: only S2 + direct) ----
    sgemm(slotA + bb * 4608, 72, 64, 2048);            // S2 = x @ h2^T
    __syncthreads();
    direct(Wt2, 2048, 64, 0, 128, bs2, 8);             // out cols 128..255
}

extern "C" void kernel_launch(void* const* d_in, const int* in_sizes, int n_in,
                              void* d_out, int out_size, void* d_ws, size_t ws_size,
                              hipStream_t stream)
{
    const float* x  = (const float*)d_in[0];
    const float* W0 = (const float*)d_in[1];
    const float* b0 = (const float*)d_in[2];
    const float* W1 = (const float*)d_in[3];
    const float* b1 = (const float*)d_in[4];
    const float* W2 = (const float*)d_in[5];
    const float* b2 = (const float*)d_in[6];
    float* out = (float*)d_out;

    char* ws = (char*)d_ws;
    _Float16* Wt0 = (_Float16*)(ws + 0);           // 256 KB
    _Float16* Wt1 = (_Float16*)(ws + 262144);      // 512 KB
    _Float16* Wt2 = (_Float16*)(ws + 786432);      // 512 KB
    (void)in_sizes; (void)n_in; (void)out_size; (void)ws_size;

    hipLaunchKernelGGL(pack_w_all, dim3(160), dim3(256), 0, stream,
                       W0, Wt0, W1, Wt1, W2, Wt2);

    hipLaunchKernelGGL(cin_fused, dim3(512), dim3(256), 0, stream,
                       x, Wt0, Wt1, Wt2, b0, b1, b2, out);
}

// Round 16
// 122.256 us; speedup vs baseline: 1.2269x; 1.2269x over previous
//
#include <hip/hip_runtime.h>
#include <hip/hip_bf16.h>
#include <cstdint>

// CIN chain: B=1024, F0=32, EMB=64, layers 128/128/128.
// cur[b,k,e] = sum_{i,j} x[b,i,e]*h[b,j,e]*W[i*fi+j,k]
//
// R16: revert R15's direct-GEMM fold (block-local S = 2/16 B-columns used
// -> 8x MFMA waste, fused 84.5 us). Back to R14's 3-kernel split
// (pack -> fused[hidden+S] -> direct[S@Wd, 16 batches/fragment]), keeping
// R15's dead-slot split-K exchange: partials go through the dead hT slot
// (barrier-separated), deleting the 16 KB xchg buffer. LDS 60 -> 44 KB
// -> 3 blocks/CU (was 2). Timed region includes a fixed ~43 us harness
// poison fill; kernel budget is what we control.

typedef _Float16 half8  __attribute__((ext_vector_type(8)));
typedef _Float16 half4_ __attribute__((ext_vector_type(4)));
typedef _Float16 half2_ __attribute__((ext_vector_type(2)));
typedef float    f32x4  __attribute__((ext_vector_type(4)));

// Pack W (fan_in,128) f32 -> chunked f16 Wt[c][m][kk] = W[c*32+kk][m].
__global__ void pack_w_all(const float* __restrict__ W0, _Float16* __restrict__ Wt0,
                           const float* __restrict__ W1, _Float16* __restrict__ Wt1,
                           const float* __restrict__ W2, _Float16* __restrict__ Wt2)
{
    __shared__ _Float16 ldsT[128 * 33];
    const int blk = blockIdx.x, t = threadIdx.x;
    const float* W;
    _Float16* Wt;
    int c;
    if (blk < 32)       { W = W0; Wt = Wt0; c = blk; }
    else if (blk < 96)  { W = W1; Wt = Wt1; c = blk - 32; }
    else                { W = W2; Wt = Wt2; c = blk - 96; }

    for (int p = t; p < 32 * 128; p += 256) {
        int kk = p >> 7, m = p & 127;
        ldsT[m * 33 + kk] = (_Float16)W[(size_t)(c * 32 + kk) * 128 + m];
    }
    __syncthreads();
    int m = t >> 1, kk0 = (t & 1) * 16;
    half8 v0, v1;
#pragma unroll
    for (int i = 0; i < 8; ++i) {
        v0[i] = ldsT[m * 33 + kk0 + i];
        v1[i] = ldsT[m * 33 + kk0 + 8 + i];
    }
    *(half8*)(Wt + (size_t)c * 4096 + t * 16)     = v0;
    *(half8*)(Wt + (size_t)c * 4096 + t * 16 + 8) = v1;
}

// Fused hidden+S kernel. Block = 2 batches, 256 thr = 4 waves (bb x ks).
__global__ __launch_bounds__(256, 3)
void cin_fused(const float* __restrict__ x,          // (1024,32,64) f32
               const _Float16* __restrict__ Wt0,
               const _Float16* __restrict__ Wt1,
               const float* __restrict__ bs0,
               const float* __restrict__ bs1,
               _Float16* __restrict__ S0,             // (1024,1024)
               _Float16* __restrict__ S1,             // (1024,2048)
               _Float16* __restrict__ S2)             // (1024,2048)
{
    __shared__ alignas(16) char smem[45056];           // 44 KB -> 3 blocks/CU
    _Float16* slotA = (_Float16*)smem;                 // 18 KB: hT0 / hJ images
    _Float16* slotB = (_Float16*)(smem + 18432);       // 18 KB: hT1 / partials
    _Float16* sX    = (_Float16*)(smem + 36864);       // 8 KB: x [bb][i*64+e]

    const int t = threadIdx.x, lane = t & 63, w = t >> 6;
    const int ks = w & 1, bb = w >> 1;
    const int lr = lane & 15, q = lane >> 4;
    const int b0 = blockIdx.x * 2;
    const int batch = b0 + bb;

    // prologue: x -> sX [i][e]; hT0 [e][i] pitch 40 -> slotA
    {
        const float4* xv = (const float4*)(x + (size_t)b0 * 2048);
#pragma unroll
        for (int s = 0; s < 4; ++s) {
            int p4 = t + s * 256;
            float4 v = xv[p4];
            int bb2 = p4 >> 9, idx = (p4 & 511) * 4;
            int i = idx >> 6, e0 = idx & 63;
            _Float16 h0 = (_Float16)v.x, h1 = (_Float16)v.y;
            _Float16 h2 = (_Float16)v.z, h3 = (_Float16)v.w;
            half4_ pk = {h0, h1, h2, h3};
            *(half4_*)(sX + bb2 * 2048 + i * 64 + e0) = pk;
            _Float16* hb = slotA + bb2 * 2560;
            hb[(e0 + 0) * 40 + i] = h0;
            hb[(e0 + 1) * 40 + i] = h1;
            hb[(e0 + 2) * 40 + i] = h2;
            hb[(e0 + 3) * 40 + i] = h3;
        }
    }
    __syncthreads();                                   // B0

    f32x4 acc[4][4];

    // barrier-free 2-deep pipelined hidden K-loop (M=64 rows, split-K by ks)
    auto kloop = [&](const _Float16* WtL, int cBeg, int cEnd, int ish,
                     const _Float16* hbase, int ph) {
#pragma unroll
        for (int mt = 0; mt < 4; ++mt)
#pragma unroll
            for (int nt = 0; nt < 4; ++nt)
                acc[mt][nt] = f32x4{0.0f, 0.0f, 0.0f, 0.0f};
        const _Float16* aG = WtL + lr * 32 + q * 8;
        const _Float16* hP = hbase + bb * (ph << 6) + lr * ph + q * 8;
        const _Float16* xP = sX + bb * 2048 + lr;
        half8 afA[4], afB[4], hvA[4], hvB[4];
        _Float16 xsA[4], xsB[4];
        auto pf = [&](half8* af, half8* hv, _Float16* xs, int c) {
            const int i  = c >> ish;
            const int j0 = (c - (i << ish)) << 5;
            const _Float16* ag = aG + (size_t)c * 4096;
#pragma unroll
            for (int mt = 0; mt < 4; ++mt) af[mt] = *(const half8*)(ag + mt * 512);
#pragma unroll
            for (int nt = 0; nt < 4; ++nt) {
                hv[nt] = *(const half8*)(hP + nt * (ph << 4) + j0);
                xs[nt] = xP[(i << 6) + (nt << 4)];
            }
        };
        auto cp = [&](half8* af, half8* hv, _Float16* xs) {
#pragma unroll
            for (int nt = 0; nt < 4; ++nt) {
                half2_ xv2 = {xs[nt], xs[nt]};
                half8 xv8 = __builtin_shufflevector(xv2, xv2, 0, 1, 0, 1, 0, 1, 0, 1);
                half8 bf = hv[nt] * xv8;
#pragma unroll
                for (int mt = 0; mt < 4; ++mt)
                    acc[mt][nt] = __builtin_amdgcn_mfma_f32_16x16x32_f16(
                        af[mt], bf, acc[mt][nt], 0, 0, 0);
            }
        };
        pf(afA, hvA, xsA, cBeg);
        for (int c = cBeg; c < cEnd; c += 2) {
            pf(afB, hvB, xsB, c + 1);
            cp(afA, hvA, xsA);
            if (c + 2 < cEnd) pf(afA, hvA, xsA, c + 2);
            cp(afB, hvB, xsB);
        }
    };

    // S_l[b][i*fi+j] = sum_e x[i,e]*h[j,e] -> global. Wave does i-tile = ks.
    auto sgemm = [&](const _Float16* hJ, int jp, int fi, _Float16* Sdst) {
        const _Float16* axp = sX + bb * 2048 + (ks * 16 + lr) * 64 + q * 8;
        const int njt = fi >> 4;
        for (int jt = 0; jt < njt; ++jt) {
            f32x4 sa = {0.0f, 0.0f, 0.0f, 0.0f};
#pragma unroll
            for (int c2 = 0; c2 < 2; ++c2) {
                half8 a = *(const half8*)(axp + c2 * 32);
                half8 b = *(const half8*)(hJ + (jt * 16 + lr) * jp + q * 8 + c2 * 32);
                sa = __builtin_amdgcn_mfma_f32_16x16x32_f16(a, b, sa, 0, 0, 0);
            }
#pragma unroll
            for (int r = 0; r < 4; ++r)
                Sdst[(size_t)batch * (32 * fi) + (ks * 16 + q * 4 + r) * fi
                     + jt * 16 + lr] = (_Float16)sa[r];
        }
    };

    // ks=1 hidden partial -> slot, hT layout [e*72 + j] (vector half4)
    auto partial_out = [&](_Float16* slot) {
#pragma unroll
        for (int mt = 0; mt < 4; ++mt)
#pragma unroll
            for (int nt = 0; nt < 4; ++nt) {
                int e = nt * 16 + lr;
                int j = mt * 16 + q * 4;
                half4_ pv;
#pragma unroll
                for (int r = 0; r < 4; ++r) pv[r] = (_Float16)acc[mt][nt][r];
                *(half4_*)(slot + bb * 4608 + e * 72 + j) = pv;
            }
    };

    // ---- phase 0 ----
    sgemm(sX + bb * 2048, 64, 32, S0);                 // S0 = x @ x^T
    kloop(Wt0, ks * 16, ks * 16 + 16, 0, slotA, 40);   // hidden rows 0..63
    if (ks == 1) partial_out(slotB);                   // slotB virgin
    __syncthreads();                                   // B1
    if (ks == 0) {
        // combine + bias -> hT1 (slotB, same addresses) + hJ1 (slotA scatter)
#pragma unroll
        for (int mt = 0; mt < 4; ++mt)
#pragma unroll
            for (int nt = 0; nt < 4; ++nt) {
                int e = nt * 16 + lr;
                int j = mt * 16 + q * 4;
                half4_ pv = *(const half4_*)(slotB + bb * 4608 + e * 72 + j);
                half4_ vh;
#pragma unroll
                for (int r = 0; r < 4; ++r) {
                    float v = acc[mt][nt][r] + (float)pv[r] + bs0[j + r];
                    vh[r] = (_Float16)v;
                    slotA[bb * 4608 + (j + r) * 72 + e] = (_Float16)v;
                }
                *(half4_*)(slotB + bb * 4608 + e * 72 + j) = vh;
            }
    }
    __syncthreads();                                   // B2

    // ---- phase 1 ----
    sgemm(slotA + bb * 4608, 72, 64, S1);              // S1 = x @ h1^T
    kloop(Wt1, ks * 32, ks * 32 + 32, 1, slotB, 72);   // hidden rows 0..63
    __syncthreads();                                   // B3: hT1 reads done
    if (ks == 1) partial_out(slotB);                   // reuse dead hT1 region
    __syncthreads();                                   // B4
    if (ks == 0) {
        // combine + bias -> hJ2 only (slotA scatter; hJ1 dead after B3)
#pragma unroll
        for (int mt = 0; mt < 4; ++mt)
#pragma unroll
            for (int nt = 0; nt < 4; ++nt) {
                int e = nt * 16 + lr;
                int j = mt * 16 + q * 4;
                half4_ pv = *(const half4_*)(slotB + bb * 4608 + e * 72 + j);
#pragma unroll
                for (int r = 0; r < 4; ++r)
                    slotA[bb * 4608 + (j + r) * 72 + e]
                        = (_Float16)(acc[mt][nt][r] + (float)pv[r] + bs1[j + r]);
            }
    }
    __syncthreads();                                   // B5

    sgemm(slotA + bb * 4608, 72, 64, S2);              // S2 = x @ h2^T
}

// Direct-output GEMM: out[b, ob+k] = S_l[b,:] . Wt_l[:, dm0+k] + 64*bias.
// 1024 waves: W<256 -> L0 (64 bt x 4 kt); <512 -> L1; else L2 (8 kt).
__global__ __launch_bounds__(256, 4)
void cin_direct(const _Float16* __restrict__ S0v, const _Float16* __restrict__ S1v,
                const _Float16* __restrict__ S2v,
                const _Float16* __restrict__ Wt0, const _Float16* __restrict__ Wt1,
                const _Float16* __restrict__ Wt2,
                const float* __restrict__ bs0, const float* __restrict__ bs1,
                const float* __restrict__ bs2,
                float* __restrict__ out)
{
    const int t = threadIdx.x, lane = t & 63;
    const int lr = lane & 15, q = lane >> 4;
    const int W = blockIdx.x * 4 + (t >> 6);

    const _Float16 *S, *Wt;
    const float* bias;
    int fan, nch, dm0, ob, idx;
    if (W < 256)      { S = S0v; Wt = Wt0; bias = bs0; fan = 1024; nch = 32; dm0 = 64; ob = 0;   idx = W; }
    else if (W < 512) { S = S1v; Wt = Wt1; bias = bs1; fan = 2048; nch = 64; dm0 = 64; ob = 64;  idx = W - 256; }
    else              { S = S2v; Wt = Wt2; bias = bs2; fan = 2048; nch = 64; dm0 = 0;  ob = 128; idx = W - 512; }
    const int bt = idx & 63, kt = idx >> 6;
    const int bbase = bt * 16;

    const _Float16* aG = Wt + (dm0 + kt * 16 + lr) * 32 + q * 8;   // + c*4096
    const _Float16* bG = S + (size_t)(bbase + lr) * fan + q * 8;   // + c*32

    f32x4 acc = {0.0f, 0.0f, 0.0f, 0.0f};
    half8 aA = *(const half8*)(aG);
    half8 bA = *(const half8*)(bG);
    for (int c = 0; c < nch; c += 2) {
        half8 aB = *(const half8*)(aG + (size_t)(c + 1) * 4096);
        half8 bB = *(const half8*)(bG + (c + 1) * 32);
        acc = __builtin_amdgcn_mfma_f32_16x16x32_f16(aA, bA, acc, 0, 0, 0);
        if (c + 2 < nch) {
            aA = *(const half8*)(aG + (size_t)(c + 2) * 4096);
            bA = *(const half8*)(bG + (c + 2) * 32);
        }
        acc = __builtin_amdgcn_mfma_f32_16x16x32_f16(aB, bB, acc, 0, 0, 0);
    }
#pragma unroll
    for (int r = 0; r < 4; ++r) {
        int kl = kt * 16 + q * 4 + r;
        out[(size_t)(bbase + lr) * 256 + ob + kl] = acc[r] + 64.0f * bias[dm0 + kl];
    }
}

extern "C" void kernel_launch(void* const* d_in, const int* in_sizes, int n_in,
                              void* d_out, int out_size, void* d_ws, size_t ws_size,
                              hipStream_t stream)
{
    const float* x  = (const float*)d_in[0];
    const float* W0 = (const float*)d_in[1];
    const float* b0 = (const float*)d_in[2];
    const float* W1 = (const float*)d_in[3];
    const float* b1 = (const float*)d_in[4];
    const float* W2 = (const float*)d_in[5];
    const float* b2 = (const float*)d_in[6];
    float* out = (float*)d_out;

    char* ws = (char*)d_ws;
    _Float16* Wt0 = (_Float16*)(ws + 0);           // 256 KB
    _Float16* Wt1 = (_Float16*)(ws + 262144);      // 512 KB
    _Float16* Wt2 = (_Float16*)(ws + 786432);      // 512 KB
    _Float16* S0  = (_Float16*)(ws + 1310720);     // 2 MB
    _Float16* S1  = (_Float16*)(ws + 3407872);     // 4 MB
    _Float16* S2  = (_Float16*)(ws + 7602176);     // 4 MB
    (void)in_sizes; (void)n_in; (void)out_size; (void)ws_size;

    hipLaunchKernelGGL(pack_w_all, dim3(160), dim3(256), 0, stream,
                       W0, Wt0, W1, Wt1, W2, Wt2);

    hipLaunchKernelGGL(cin_fused, dim3(512), dim3(256), 0, stream,
                       x, Wt0, Wt1, b0, b1, S0, S1, S2);

    hipLaunchKernelGGL(cin_direct, dim3(256), dim3(256), 0, stream,
                       S0, S1, S2, Wt0, Wt1, Wt2, b0, b1, b2, out);
}